// Round 5
// baseline (254.081 us; speedup 1.0000x reference)
//
#include <hip/hip_runtime.h>

// Problem constants (fixed by reference setup_inputs)
#define NB 8
#define NC 19
#define NH 512
#define NW 512
#define HWP (NH * NW)

#define TW 32
#define TH 16
#define HB_W 40              // LDS row stride in pixels (quad-aligned halo span)
#define HB_H 18              // halo rows
#define PLANE (HB_W * HB_H)  // 720
#define NQ_W 10              // float4-quads per halo row
#define NQUAD (HB_H * NQ_W)  // 180
#define NPAIR 10             // ceil(19/2) fp16 channel pairs
#define NTHREADS 256
#define NBLOCKS 4096

typedef _Float16 h2 __attribute__((ext_vector_type(2)));

static __device__ __forceinline__ unsigned int h2_to_u(h2 v) {
    return __builtin_bit_cast(unsigned int, v);
}
static __device__ __forceinline__ h2 u_to_h2(unsigned int u) {
    return __builtin_bit_cast(h2, u);
}

#if __has_builtin(__builtin_amdgcn_cvt_pkrtz)
static __device__ __forceinline__ h2 cvt_pk2(float a, float b) {
    return __builtin_bit_cast(h2, __builtin_amdgcn_cvt_pkrtz(a, b));
}
#else
static __device__ __forceinline__ h2 cvt_pk2(float a, float b) {
    h2 r; r[0] = (_Float16)a; r[1] = (_Float16)b; return r;
}
#endif

#if __has_builtin(__builtin_amdgcn_fdot2)
static __device__ __forceinline__ float fdot2f(h2 a, h2 b, float c) {
    return __builtin_amdgcn_fdot2(a, b, c, false);
}
#else
static __device__ __forceinline__ float fdot2f(h2 a, h2 b, float c) {
    return c + (float)a[0] * (float)b[0] + (float)a[1] * (float)b[1];
}
#endif

// LDS: 10 planes of fp16-pair probs (720 px @ stride 40) + target plane.
// 10*720*4 + 720*4 = 31680 B -> 5 blocks/CU.
__global__ __launch_bounds__(NTHREADS, 5) void bl_main(
    const float* __restrict__ pred, const int* __restrict__ target,
    float* __restrict__ partial, unsigned int* __restrict__ counter,
    float* __restrict__ out)
{
    __shared__ unsigned int e_lds[NPAIR][PLANE];
    __shared__ int t_lds[PLANE];

    const int tid = threadIdx.x;
    // XCD-aware swizzle: each XCD gets one full image in row-major tile order
    const int n = blockIdx.x;                // 0..4095
    const int tI = ((n & 7) << 9) + (n >> 3);
    const int bz = tI >> 9;                  // image 0..7
    const int rem = tI & 511;
    const int by = rem >> 4;                 // 0..31
    const int bx = rem & 15;                 // 0..15

    const int h0 = by * TH - 1;              // first halo row (global)
    const int gx0 = bx * TW - 4;             // LDS col 0 (global, 16B-aligned)
    const float* predb = pred + (size_t)bz * NC * HWP;
    const int* tgtb = target + (size_t)bz * HWP;

    // ---- Stage (tid < 180): one aligned 4-pixel quad each, STREAMING ----
    if (tid < NQUAD) {
        const int r = tid / NQ_W;            // halo row 0..17
        const int q = tid - r * NQ_W;        // quad 0..9
        const int gh = h0 + r;
        const int gq = gx0 + (q << 2);       // quad's global col start
        const int ghc = min(max(gh, 0), NH - 1);
        const int gqc = min(max(gq, 0), NW - 4);
        const bool rowok = (gh >= 0) && (gh < NH);
        const float* src = predb + (size_t)ghc * NW + gqc;
        const int lb = r * HB_W + (q << 2);  // 16B-aligned LDS index

        float s0 = 0.f, s1 = 0.f, s2 = 0.f, s3 = 0.f;

        // Low live-register loop: unnormalized exp pairs go straight to LDS.
        // Frees ~40 VGPRs vs the register-block version -> compiler can hoist
        // the independent strided loads far ahead (one latency exposure).
        #pragma unroll
        for (int j = 0; j < NPAIR; ++j) {
            const float4 a = *reinterpret_cast<const float4*>(
                src + (size_t)(2 * j) * HWP);
            const float ea0 = __expf(a.x), ea1 = __expf(a.y);
            const float ea2 = __expf(a.z), ea3 = __expf(a.w);
            float eb0 = 0.f, eb1 = 0.f, eb2 = 0.f, eb3 = 0.f;
            if (j < NPAIR - 1) {             // channel 19 doesn't exist
                const float4 b = *reinterpret_cast<const float4*>(
                    src + (size_t)(2 * j + 1) * HWP);
                eb0 = __expf(b.x); eb1 = __expf(b.y);
                eb2 = __expf(b.z); eb3 = __expf(b.w);
            }
            s0 += ea0 + eb0; s1 += ea1 + eb1;
            s2 += ea2 + eb2; s3 += ea3 + eb3;
            *reinterpret_cast<uint4*>(&e_lds[j][lb]) = make_uint4(
                h2_to_u(cvt_pk2(ea0, eb0)), h2_to_u(cvt_pk2(ea1, eb1)),
                h2_to_u(cvt_pk2(ea2, eb2)), h2_to_u(cvt_pk2(ea3, eb3)));
        }

        // per-pixel inverse sums (0 for padding folds zero-pad in exactly)
        const bool ok0 = rowok && (gq + 0 >= 0) && (gq + 0 < NW);
        const bool ok1 = rowok && (gq + 1 >= 0) && (gq + 1 < NW);
        const bool ok2 = rowok && (gq + 2 >= 0) && (gq + 2 < NW);
        const bool ok3 = rowok && (gq + 3 >= 0) && (gq + 3 < NW);
        const float i0 = ok0 ? __builtin_amdgcn_rcpf(s0) : 0.f;
        const float i1 = ok1 ? __builtin_amdgcn_rcpf(s1) : 0.f;
        const float i2 = ok2 ? __builtin_amdgcn_rcpf(s2) : 0.f;
        const float i3 = ok3 ? __builtin_amdgcn_rcpf(s3) : 0.f;
        h2 ih0, ih1, ih2, ih3;
        ih0[0] = (_Float16)i0; ih0[1] = ih0[0];
        ih1[0] = (_Float16)i1; ih1[1] = ih1[0];
        ih2[0] = (_Float16)i2; ih2[1] = ih2[0];
        ih3[0] = (_Float16)i3; ih3[1] = ih3[0];

        // same-thread LDS roundtrip normalize (off critical resource: LDS pipe)
        #pragma unroll
        for (int j = 0; j < NPAIR; ++j) {
            uint4 v = *reinterpret_cast<const uint4*>(&e_lds[j][lb]);
            v.x = h2_to_u(u_to_h2(v.x) * ih0);
            v.y = h2_to_u(u_to_h2(v.y) * ih1);
            v.z = h2_to_u(u_to_h2(v.z) * ih2);
            v.w = h2_to_u(u_to_h2(v.w) * ih3);
            *reinterpret_cast<uint4*>(&e_lds[j][lb]) = v;
        }

        const int4 tv = *reinterpret_cast<const int4*>(
            tgtb + (size_t)ghc * NW + gqc);
        int4 tw;
        tw.x = ok0 ? tv.x : 31;
        tw.y = ok1 ? tv.y : 31;
        tw.z = ok2 ? tv.z : 31;
        tw.w = ok3 ? tv.w : 31;
        *reinterpret_cast<int4*>(&t_lds[lb]) = tw;
    }
    __syncthreads();

    // ---- Conv (tid >= 128): thread owns 2 cols x 2 rows of outputs ----
    float acc = 0.f;
    if (tid >= 128) {
        const int t = tid - 128;
        const int u = t & 15;        // col pair: output cols 2u, 2u+1
        const int s = t >> 4;        // strip:   output rows 2s, 2s+1
        const int r0 = 2 * s;        // first halo row of 4-row window
        const int cw = 2 * u + 2;    // leftmost loaded halo col (even)

        // target window: 4 rows x cols [1..4]
        int w[4][4];
        #pragma unroll
        for (int r = 0; r < 4; ++r) {
            const int base = (r0 + r) * HB_W + cw;
            const int2 mdl = *reinterpret_cast<const int2*>(&t_lds[base + 2]);
            w[r][0] = t_lds[base + 1];
            w[r][1] = mdl.x;
            w[r][2] = mdl.y;
            w[r][3] = t_lds[base + 4];
        }

        unsigned int rm[2][4];
        #pragma unroll
        for (int r = 0; r < 4; ++r) {
            const unsigned b1 = 1u << w[r][0];
            const unsigned b2 = 1u << w[r][1];
            const unsigned b3 = 1u << w[r][2];
            const unsigned b4 = 1u << w[r][3];
            const unsigned mm = b2 | b3;
            rm[0][r] = mm | b1;
            rm[1][r] = mm | b4;
        }
        unsigned int mpx[2][2];
        #pragma unroll
        for (int jc = 0; jc < 2; ++jc) {
            const unsigned mid = rm[jc][1] | rm[jc][2];
            #pragma unroll
            for (int k = 0; k < 2; ++k) {
                unsigned m = mid | rm[jc][k ? 3 : 0];
                // popc==1 <=> all 9 (incl. padding sentinel) equal => tb = 0
                m = (__popc(m) == 1) ? 0u : (m & 0x7FFFFu);
                mpx[jc][k] = m;
                acc += (float)__popc(m);        // sum of tb^2
            }
        }

        h2 one2;  one2[0] = (_Float16)1.f;  one2[1] = (_Float16)1.f;
        h2 nine2; nine2[0] = (_Float16)9.f; nine2[1] = (_Float16)9.f;

        #pragma unroll
        for (int j = 0; j < NPAIR; ++j) {
            const unsigned int* plane = &e_lds[j][0];
            h2 rs[2][4];   // [col-chain][row] horizontal 3-sums
            h2 ctr[2][2];  // [col-chain][k] center probs
            #pragma unroll
            for (int r = 0; r < 4; ++r) {
                const int base = (r0 + r) * HB_W + cw;
                const uint2 pm = *reinterpret_cast<const uint2*>(&plane[base + 2]);
                const h2 v1 = u_to_h2(plane[base + 1]);
                const h2 v2 = u_to_h2(pm.x);
                const h2 v3 = u_to_h2(pm.y);
                const h2 v4 = u_to_h2(plane[base + 4]);
                const h2 tm = v2 + v3;
                rs[0][r] = v1 + tm;
                rs[1][r] = tm + v4;
                if (r == 1) { ctr[0][0] = v2; ctr[1][0] = v3; }
                if (r == 2) { ctr[0][1] = v2; ctr[1][1] = v3; }
            }
            #pragma unroll
            for (int jc = 0; jc < 2; ++jc) {
                const h2 midv = rs[jc][1] + rs[jc][2];
                #pragma unroll
                for (int k = 0; k < 2; ++k) {
                    const h2 S = midv + rs[jc][k ? 3 : 0];
                    const h2 lap = ctr[jc][k] * nine2 - S;          // 9c - sum9
                    const h2 ab = u_to_h2(h2_to_u(lap) & 0x7FFF7FFFu);
                    h2 mn;
                    mn[0] = ab[0] < one2[0] ? ab[0] : one2[0];
                    mn[1] = ab[1] < one2[1] ? ab[1] : one2[1];
                    acc = fdot2f(mn, mn, acc);                      // + pb^2
                    const unsigned bits = (mpx[jc][k] >> (2 * j)) & 3u;
                    const unsigned nt = (bits & 1u ? 0x0000C000u : 0u) |
                                        (bits & 2u ? 0xC0000000u : 0u);
                    acc = fdot2f(mn, u_to_h2(nt), acc);             // - 2 tb pb
                }
            }
        }
    }

    // ---- block reduction (all 4 waves; waves 0-1 contribute 0) ----
    #pragma unroll
    for (int off = 32; off > 0; off >>= 1)
        acc += __shfl_down(acc, off, 64);

    __shared__ float wsum[NTHREADS / 64];
    if ((tid & 63) == 0) wsum[tid >> 6] = acc;
    __syncthreads();

    // ---- fused final reduction: last-arriving block sums all partials ----
    __shared__ int last_flag;
    if (tid == 0) {
        float s = 0.f;
        #pragma unroll
        for (int i = 0; i < NTHREADS / 64; ++i) s += wsum[i];
        partial[n] = s;
        __threadfence();   // agent-scope release: flush partial past XCD L2
        const unsigned old = __hip_atomic_fetch_add(
            counter, 1u, __ATOMIC_ACQ_REL, __HIP_MEMORY_SCOPE_AGENT);
        last_flag = (old == NBLOCKS - 1);
    }
    __syncthreads();

    if (last_flag) {
        __threadfence();   // agent-scope acquire for every wave in this block
        float s = 0.f;
        #pragma unroll 4
        for (int i = tid; i < NBLOCKS; i += NTHREADS)
            s += __hip_atomic_load(&partial[i], __ATOMIC_RELAXED,
                                   __HIP_MEMORY_SCOPE_AGENT);
        #pragma unroll
        for (int off = 32; off > 0; off >>= 1)
            s += __shfl_down(s, off, 64);
        if ((tid & 63) == 0) wsum[tid >> 6] = s;
        __syncthreads();
        if (tid == 0) {
            const float t4 = wsum[0] + wsum[1] + wsum[2] + wsum[3];
            out[0] = t4 * (1.0f / ((float)NB * NC * NH * NW));
        }
    }
}

extern "C" void kernel_launch(void* const* d_in, const int* in_sizes, int n_in,
                              void* d_out, int out_size, void* d_ws, size_t ws_size,
                              hipStream_t stream) {
    const float* pred = (const float*)d_in[0];
    const int* target = (const int*)d_in[1];
    float* partial = (float*)d_ws;
    unsigned int* counter = (unsigned int*)((char*)d_ws + NBLOCKS * sizeof(float));

    hipMemsetAsync(counter, 0, sizeof(unsigned int), stream);
    bl_main<<<dim3(NBLOCKS), NTHREADS, 0, stream>>>(
        pred, target, partial, counter, (float*)d_out);
}

// Round 6
// 37.550 us; speedup vs baseline: 6.7665x; 6.7665x over previous
//
#include <hip/hip_runtime.h>

// Problem constants (fixed by reference setup_inputs)
#define NB 8
#define NC 19
#define NH 512
#define NW 512
#define HWP (NH * NW)

#define TW 32
#define TH 16
#define HB_W 40              // LDS row stride in pixels (quad-aligned halo span)
#define HB_H 18              // halo rows
#define PLANE (HB_W * HB_H)  // 720
#define NQ_W 10              // float4-quads per halo row
#define NQUAD (HB_H * NQ_W)  // 180
#define NPAIR 10             // ceil(19/2) fp16 channel pairs
#define NTHREADS 256
#define NBLOCKS 4096

typedef _Float16 h2 __attribute__((ext_vector_type(2)));

static __device__ __forceinline__ unsigned int h2_to_u(h2 v) {
    return __builtin_bit_cast(unsigned int, v);
}
static __device__ __forceinline__ h2 u_to_h2(unsigned int u) {
    return __builtin_bit_cast(h2, u);
}

#if __has_builtin(__builtin_amdgcn_cvt_pkrtz)
static __device__ __forceinline__ h2 cvt_pk2(float a, float b) {
    return __builtin_bit_cast(h2, __builtin_amdgcn_cvt_pkrtz(a, b));
}
#else
static __device__ __forceinline__ h2 cvt_pk2(float a, float b) {
    h2 r; r[0] = (_Float16)a; r[1] = (_Float16)b; return r;
}
#endif

#if __has_builtin(__builtin_amdgcn_fdot2)
static __device__ __forceinline__ float fdot2f(h2 a, h2 b, float c) {
    return __builtin_amdgcn_fdot2(a, b, c, false);
}
#else
static __device__ __forceinline__ float fdot2f(h2 a, h2 b, float c) {
    return c + (float)a[0] * (float)b[0] + (float)a[1] * (float)b[1];
}
#endif

// LDS: 10 planes of NORMALIZED fp16-pair probs (720 px @ stride 40) + target.
// 31680 B -> 5 blocks/CU. VGPR capped ~102 by launch_bounds(256,5).
__global__ __launch_bounds__(NTHREADS, 5) void bl_main(
    const float* __restrict__ pred, const int* __restrict__ target,
    float* __restrict__ partial)
{
    __shared__ unsigned int e_lds[NPAIR][PLANE];
    __shared__ int t_lds[PLANE];

    const int tid = threadIdx.x;
    // XCD-aware swizzle: each XCD gets one full image in row-major tile order
    const int n = blockIdx.x;                // 0..4095
    const int tI = ((n & 7) << 9) + (n >> 3);
    const int bz = tI >> 9;                  // image 0..7
    const int rem = tI & 511;
    const int by = rem >> 4;                 // 0..31
    const int bx = rem & 15;                 // 0..15

    const int h0 = by * TH - 1;              // first halo row (global)
    const int gx0 = bx * TW - 4;             // LDS col 0 (global, 16B-aligned)
    const float* predb = pred + (size_t)bz * NC * HWP;
    const int* tgtb = target + (size_t)bz * HWP;

    // ---- Stage (tid < 180): one aligned 4-pixel quad each ----
    if (tid < NQUAD) {
        const int r = tid / NQ_W;            // halo row 0..17
        const int q = tid - r * NQ_W;        // quad 0..9
        const int gh = h0 + r;
        const int gq = gx0 + (q << 2);       // quad's global col start
        const int ghc = min(max(gh, 0), NH - 1);
        const int gqc = min(max(gq, 0), NW - 4);
        const bool rowok = (gh >= 0) && (gh < NH);
        const float* src = predb + (size_t)ghc * NW + gqc;

        // Issue ALL 19 strided loads (and the target load) before any use:
        // one HBM latency exposure instead of several small batches.
        float4 av[NPAIR];
        float4 bv[NPAIR - 1];
        #pragma unroll
        for (int j = 0; j < NPAIR; ++j)
            av[j] = *reinterpret_cast<const float4*>(
                src + (size_t)(2 * j) * HWP);
        #pragma unroll
        for (int j = 0; j < NPAIR - 1; ++j)
            bv[j] = *reinterpret_cast<const float4*>(
                src + (size_t)(2 * j + 1) * HWP);
        const int4 tv = *reinterpret_cast<const int4*>(
            tgtb + (size_t)ghc * NW + gqc);

        float s0 = 0.f, s1 = 0.f, s2 = 0.f, s3 = 0.f;
        unsigned int pkv[NPAIR][4];

        #pragma unroll
        for (int j = 0; j < NPAIR; ++j) {
            const float ea0 = __expf(av[j].x), ea1 = __expf(av[j].y);
            const float ea2 = __expf(av[j].z), ea3 = __expf(av[j].w);
            float eb0 = 0.f, eb1 = 0.f, eb2 = 0.f, eb3 = 0.f;
            if (j < NPAIR - 1) {             // channel 19 doesn't exist
                eb0 = __expf(bv[j].x); eb1 = __expf(bv[j].y);
                eb2 = __expf(bv[j].z); eb3 = __expf(bv[j].w);
            }
            s0 += ea0 + eb0; s1 += ea1 + eb1;
            s2 += ea2 + eb2; s3 += ea3 + eb3;
            pkv[j][0] = h2_to_u(cvt_pk2(ea0, eb0));
            pkv[j][1] = h2_to_u(cvt_pk2(ea1, eb1));
            pkv[j][2] = h2_to_u(cvt_pk2(ea2, eb2));
            pkv[j][3] = h2_to_u(cvt_pk2(ea3, eb3));
        }

        // per-pixel normalize in registers (inv = 0 folds zero-padding in)
        #define NORM_PX(E, SE, OK)                                          \
        {                                                                   \
            const float invf = (OK) ? __builtin_amdgcn_rcpf(SE) : 0.f;      \
            const _Float16 ih = (_Float16)invf;                             \
            h2 ih2v; ih2v[0] = ih; ih2v[1] = ih;                            \
            _Pragma("unroll")                                               \
            for (int j = 0; j < NPAIR; ++j)                                 \
                pkv[j][E] = h2_to_u(u_to_h2(pkv[j][E]) * ih2v);             \
        }
        const bool ok0 = rowok && (gq + 0 >= 0) && (gq + 0 < NW);
        const bool ok1 = rowok && (gq + 1 >= 0) && (gq + 1 < NW);
        const bool ok2 = rowok && (gq + 2 >= 0) && (gq + 2 < NW);
        const bool ok3 = rowok && (gq + 3 >= 0) && (gq + 3 < NW);
        NORM_PX(0, s0, ok0) NORM_PX(1, s1, ok1)
        NORM_PX(2, s2, ok2) NORM_PX(3, s3, ok3)
        #undef NORM_PX

        const int lb = r * HB_W + (q << 2);  // 16B-aligned LDS index
        #pragma unroll
        for (int j = 0; j < NPAIR; ++j) {
            *reinterpret_cast<uint4*>(&e_lds[j][lb]) =
                make_uint4(pkv[j][0], pkv[j][1], pkv[j][2], pkv[j][3]);
        }

        int4 tw;
        tw.x = ok0 ? tv.x : 31;
        tw.y = ok1 ? tv.y : 31;
        tw.z = ok2 ? tv.z : 31;
        tw.w = ok3 ? tv.w : 31;
        *reinterpret_cast<int4*>(&t_lds[lb]) = tw;
    }
    __syncthreads();

    // ---- Conv (tid >= 128): thread owns 2 cols x 2 rows of outputs ----
    float acc = 0.f;
    if (tid >= 128) {
        const int t = tid - 128;
        const int u = t & 15;        // col pair: output cols 2u, 2u+1
        const int s = t >> 4;        // strip:   output rows 2s, 2s+1
        const int r0 = 2 * s;        // first halo row of 4-row window
        const int cw = 2 * u + 2;    // leftmost loaded halo col (even)

        // target window: 4 rows x cols [1..4]
        int w[4][4];
        #pragma unroll
        for (int r = 0; r < 4; ++r) {
            const int base = (r0 + r) * HB_W + cw;
            const int2 mdl = *reinterpret_cast<const int2*>(&t_lds[base + 2]);
            w[r][0] = t_lds[base + 1];
            w[r][1] = mdl.x;
            w[r][2] = mdl.y;
            w[r][3] = t_lds[base + 4];
        }

        unsigned int rm[2][4];
        #pragma unroll
        for (int r = 0; r < 4; ++r) {
            const unsigned b1 = 1u << w[r][0];
            const unsigned b2 = 1u << w[r][1];
            const unsigned b3 = 1u << w[r][2];
            const unsigned b4 = 1u << w[r][3];
            const unsigned mm = b2 | b3;
            rm[0][r] = mm | b1;
            rm[1][r] = mm | b4;
        }
        unsigned int mpx[2][2];
        #pragma unroll
        for (int jc = 0; jc < 2; ++jc) {
            const unsigned mid = rm[jc][1] | rm[jc][2];
            #pragma unroll
            for (int k = 0; k < 2; ++k) {
                unsigned m = mid | rm[jc][k ? 3 : 0];
                // popc==1 <=> all 9 (incl. padding sentinel) equal => tb = 0
                m = (__popc(m) == 1) ? 0u : (m & 0x7FFFFu);
                mpx[jc][k] = m;
                acc += (float)__popc(m);        // sum of tb^2
            }
        }

        h2 one2;  one2[0] = (_Float16)1.f;  one2[1] = (_Float16)1.f;
        h2 nine2; nine2[0] = (_Float16)9.f; nine2[1] = (_Float16)9.f;

        #pragma unroll
        for (int j = 0; j < NPAIR; ++j) {
            const unsigned int* plane = &e_lds[j][0];
            h2 rs[2][4];   // [col-chain][row] horizontal 3-sums
            h2 ctr[2][2];  // [col-chain][k] center probs
            #pragma unroll
            for (int r = 0; r < 4; ++r) {
                const int base = (r0 + r) * HB_W + cw;
                const uint2 pm = *reinterpret_cast<const uint2*>(&plane[base + 2]);
                const h2 v1 = u_to_h2(plane[base + 1]);
                const h2 v2 = u_to_h2(pm.x);
                const h2 v3 = u_to_h2(pm.y);
                const h2 v4 = u_to_h2(plane[base + 4]);
                const h2 tm = v2 + v3;
                rs[0][r] = v1 + tm;
                rs[1][r] = tm + v4;
                if (r == 1) { ctr[0][0] = v2; ctr[1][0] = v3; }
                if (r == 2) { ctr[0][1] = v2; ctr[1][1] = v3; }
            }
            #pragma unroll
            for (int jc = 0; jc < 2; ++jc) {
                const h2 midv = rs[jc][1] + rs[jc][2];
                #pragma unroll
                for (int k = 0; k < 2; ++k) {
                    const h2 S = midv + rs[jc][k ? 3 : 0];
                    const h2 lap = ctr[jc][k] * nine2 - S;          // 9c - sum9
                    const h2 ab = u_to_h2(h2_to_u(lap) & 0x7FFF7FFFu);
                    h2 mn;
                    mn[0] = ab[0] < one2[0] ? ab[0] : one2[0];
                    mn[1] = ab[1] < one2[1] ? ab[1] : one2[1];
                    acc = fdot2f(mn, mn, acc);                      // + pb^2
                    const unsigned bits = (mpx[jc][k] >> (2 * j)) & 3u;
                    const unsigned nt = (bits & 1u ? 0x0000C000u : 0u) |
                                        (bits & 2u ? 0xC0000000u : 0u);
                    acc = fdot2f(mn, u_to_h2(nt), acc);             // - 2 tb pb
                }
            }
        }
    }

    // ---- block reduction (all 4 waves; waves 0-1 contribute 0) ----
    #pragma unroll
    for (int off = 32; off > 0; off >>= 1)
        acc += __shfl_down(acc, off, 64);

    __shared__ float wsum[NTHREADS / 64];
    if ((tid & 63) == 0) wsum[tid >> 6] = acc;
    __syncthreads();
    if (tid == 0) {
        float s = 0.f;
        #pragma unroll
        for (int i = 0; i < NTHREADS / 64; ++i) s += wsum[i];
        partial[n] = s;
    }
}

__global__ __launch_bounds__(1024) void bl_reduce(
    const float4* __restrict__ partial, float* __restrict__ out)
{
    // exactly 4096 partials = 1024 threads x float4
    const float4 v = partial[threadIdx.x];
    float s = v.x + v.y + v.z + v.w;
    #pragma unroll
    for (int off = 32; off > 0; off >>= 1)
        s += __shfl_down(s, off, 64);
    __shared__ float wsum[16];
    if ((threadIdx.x & 63) == 0) wsum[threadIdx.x >> 6] = s;
    __syncthreads();
    if (threadIdx.x == 0) {
        float t = 0.f;
        #pragma unroll
        for (int i = 0; i < 16; ++i) t += wsum[i];
        out[0] = t * (1.0f / ((float)NB * NC * NH * NW));
    }
}

extern "C" void kernel_launch(void* const* d_in, const int* in_sizes, int n_in,
                              void* d_out, int out_size, void* d_ws, size_t ws_size,
                              hipStream_t stream) {
    const float* pred = (const float*)d_in[0];
    const int* target = (const int*)d_in[1];
    float* partial = (float*)d_ws;

    bl_main<<<dim3(NBLOCKS), NTHREADS, 0, stream>>>(pred, target, partial);
    bl_reduce<<<1, 1024, 0, stream>>>((const float4*)partial, (float*)d_out);
}